// Round 1
// baseline (169.443 us; speedup 1.0000x reference)
//
#include <hip/hip_runtime.h>
#include <hip/hip_bf16.h>
#include <stdint.h>

// Problem constants
#define BB 8
#define SS 1024
#define DD 512
#define MROWS (BB*SS)        // 8192
#define NCOLS (2*DD)         // 1024 (Q cols 0..511, K cols 512..1023)
#define NEG_EPS 1e-9f
#define INV_S (1.0f/1024.0f)

typedef __attribute__((ext_vector_type(8))) __bf16 bf16x8;
typedef __attribute__((ext_vector_type(4))) __bf16 bf16x4;
typedef __attribute__((ext_vector_type(4))) float f32x4;

__device__ __forceinline__ void gload_lds16(const void* g, void* l) {
    __builtin_amdgcn_global_load_lds(
        (const __attribute__((address_space(1))) void*)g,
        (__attribute__((address_space(3))) void*)l,
        16, 0, 0);
}

// ---------------- f32 -> bf16 conversion ----------------
__global__ __launch_bounds__(256) void f32_to_bf16(const float* __restrict__ src,
                                                   __bf16* __restrict__ dst, int n) {
    int i = (blockIdx.x * blockDim.x + threadIdx.x) * 4;
    int stride = gridDim.x * blockDim.x * 4;
    for (; i < n; i += stride) {
        f32x4 v = *(const f32x4*)(src + i);
        bf16x4 o;
        o[0] = (__bf16)v[0]; o[1] = (__bf16)v[1];
        o[2] = (__bf16)v[2]; o[3] = (__bf16)v[3];
        *(bf16x4*)(dst + i) = o;
    }
}

// ---------------- GEMM: [8192x512] @ [1024x512]^T -> bf16 [8192x1024] ----------------
// A = context (bf16), Bt = concat(Wq, Wk) rows as [N][K] (i.e. B^T layout)
__global__ __launch_bounds__(256) void gemm_qk(const __bf16* __restrict__ A,
                                               const __bf16* __restrict__ Bt,
                                               const float* __restrict__ bq,
                                               const float* __restrict__ bk,
                                               __bf16* __restrict__ C) {
    __shared__ alignas(16) __bf16 As[128 * 32];
    __shared__ alignas(16) __bf16 Bs[128 * 32];
    const int tid  = threadIdx.x;
    const int lane = tid & 63;
    const int wave = tid >> 6;
    const int wr = wave >> 1, wc = wave & 1;
    const int bm = blockIdx.x & 63, bn = blockIdx.x >> 6;

    f32x4 acc[4][4] = {};
    const int koff = (lane >> 4) * 8;
    const int frow = lane & 15;

    for (int kt = 0; kt < DD; kt += 32) {
        #pragma unroll
        for (int ld = 0; ld < 2; ++ld) {
            int chunk = ld * 256 + tid;
            int row = chunk >> 2;
            int kc  = (chunk & 3) * 8;
            const __bf16* ga = A  + (size_t)(bm * 128 + row) * DD + kt + kc;
            const __bf16* gb = Bt + (size_t)(bn * 128 + row) * DD + kt + kc;
            // wave-uniform LDS base; HW adds lane*16B
            gload_lds16(ga, (void*)(As + (size_t)(ld * 256 + wave * 64) * 8));
            gload_lds16(gb, (void*)(Bs + (size_t)(ld * 256 + wave * 64) * 8));
        }
        __syncthreads();
        bf16x8 av[4], bv[4];
        #pragma unroll
        for (int m = 0; m < 4; ++m)
            av[m] = *(const bf16x8*)(As + (wr * 64 + m * 16 + frow) * 32 + koff);
        #pragma unroll
        for (int n = 0; n < 4; ++n)
            bv[n] = *(const bf16x8*)(Bs + (wc * 64 + n * 16 + frow) * 32 + koff);
        #pragma unroll
        for (int m = 0; m < 4; ++m)
            #pragma unroll
            for (int n = 0; n < 4; ++n)
                acc[m][n] = __builtin_amdgcn_mfma_f32_16x16x32_bf16(av[m], bv[n], acc[m][n], 0, 0, 0);
        __syncthreads();
    }

    // epilogue: C/D layout col = lane&15, row = (lane>>4)*4 + reg
    #pragma unroll
    for (int m = 0; m < 4; ++m) {
        int row = bm * 128 + wr * 64 + m * 16 + (lane >> 4) * 4;
        #pragma unroll
        for (int n = 0; n < 4; ++n) {
            int col = bn * 128 + wc * 64 + n * 16 + frow;
            float bias = (col < DD) ? bq[col] : bk[col - DD];
            #pragma unroll
            for (int rg = 0; rg < 4; ++rg) {
                C[(size_t)(row + rg) * NCOLS + col] = (__bf16)(acc[m][n][rg] + bias);
            }
        }
    }
}

// ---------------- band dots + 2-way softmax ----------------
// qk: bf16 [8192][1024], Q at cols 0..511, K at cols 512..1023
__global__ __launch_bounds__(256) void band_softmax(const __bf16* __restrict__ qk,
                                                    const int* __restrict__ eos,
                                                    float* __restrict__ pp,
                                                    float* __restrict__ pm,
                                                    float* __restrict__ uniV) {
    int row  = blockIdx.x * 4 + (threadIdx.x >> 6);   // one wave per row
    int lane = threadIdx.x & 63;
    int b = row >> 10, s = row & 1023;

    const __bf16* Qr = qk + (size_t)row * NCOLS;
    bf16x8 qv = *(const bf16x8*)(Qr + lane * 8);

    bool hasP = (s < SS - 1), hasM = (s > 0);
    float sp = 0.f, sm = 0.f;
    if (hasP) {
        bf16x8 kv = *(const bf16x8*)(qk + (size_t)(row + 1) * NCOLS + DD + lane * 8);
        #pragma unroll
        for (int j = 0; j < 8; ++j) sp += (float)qv[j] * (float)kv[j];
    }
    if (hasM) {
        bf16x8 kv = *(const bf16x8*)(qk + (size_t)(row - 1) * NCOLS + DD + lane * 8);
        #pragma unroll
        for (int j = 0; j < 8; ++j) sm += (float)qv[j] * (float)kv[j];
    }
    #pragma unroll
    for (int off = 32; off > 0; off >>= 1) {
        sp += __shfl_xor(sp, off);
        sm += __shfl_xor(sm, off);
    }
    if (lane == 0) {
        float s_plus  = sp * (1.0f / (float)DD);
        float s_minus = sm * (1.0f / (float)DD);
        bool vp = hasP && (eos[(size_t)b * SS * SS + (size_t)s * SS + (s + 1)] != 0);
        bool vm = hasM && (eos[(size_t)b * SS * SS + (size_t)s * SS + (s - 1)] != 0);
        float opp, opm, ouni;
        if (!vp && !vm) {
            opp = INV_S; opm = INV_S; ouni = INV_S;   // all-masked row -> uniform softmax
        } else {
            float mx = -3.0e38f;
            if (vp) mx = s_plus;
            if (vm) mx = fmaxf(mx, s_minus);
            float ep = vp ? __expf(s_plus - mx) : 0.f;
            float em = vm ? __expf(s_minus - mx) : 0.f;
            float inv = 1.f / (ep + em);
            opp = ep * inv; opm = em * inv; ouni = 0.f;
        }
        pp[row] = opp; pm[row] = opm; uniV[row] = ouni;
    }
}

// ---------------- per-batch scan of L = log(na_band + eps) ----------------
__global__ __launch_bounds__(1024) void scan_kernel(const float* __restrict__ prior,
                                                    const float* __restrict__ pp,
                                                    const float* __restrict__ pm,
                                                    float* __restrict__ Cbuf) {
    int b = blockIdx.x;
    int j = threadIdx.x;
    __shared__ float sb[1024];
    float Lj = 0.f;
    if (j < SS - 1) {
        float pr = prior[((size_t)b * SS + j) * SS + (j + 1)];
        float prod = pp[b * SS + j] * pm[b * SS + j + 1];
        float na = pr + (1.f - pr) * sqrtf(prod + NEG_EPS);
        Lj = __logf(na + NEG_EPS);
    }
    sb[j] = Lj;
    __syncthreads();
    for (int off = 1; off < 1024; off <<= 1) {
        float v = (j >= off) ? sb[j - off] : 0.f;
        __syncthreads();
        sb[j] += v;
        __syncthreads();
    }
    float Cj = (j == 0) ? 0.f : sb[j - 1];   // exclusive prefix sum
    Cbuf[b * SS + j] = Cj;
}

// ---------------- dense fill of both outputs ----------------
__global__ __launch_bounds__(256) void fill_kernel(const float* __restrict__ prior,
                                                   const float* __restrict__ pp,
                                                   const float* __restrict__ pm,
                                                   const float* __restrict__ uniV,
                                                   const float* __restrict__ Cbuf,
                                                   float* __restrict__ gout,
                                                   float* __restrict__ naout) {
    int r = blockIdx.x;
    int b = r >> 10, q = r & 1023;
    int k0 = threadIdx.x * 4;
    size_t rowoff = (size_t)r * SS;

    f32x4 pr4 = *(const f32x4*)(prior + rowoff + k0);
    f32x4 uk4 = *(const f32x4*)(uniV + (b << 10) + k0);
    f32x4 C4  = *(const f32x4*)(Cbuf + (b << 10) + k0);
    float uniq = uniV[r];
    float ppq  = pp[r];
    float pmq  = pm[r];
    float Cq   = Cbuf[r];
    float ppp  = (q > 0)      ? pp[r - 1] : 0.f;   // attn[q-1 row]'s plus = attn[q-1, q]
    float pmn  = (q < SS - 1) ? pm[r + 1] : 0.f;   // attn[q+1 row]'s minus = attn[q+1, q]

    f32x4 g4, na4;
    #pragma unroll
    for (int j = 0; j < 4; ++j) {
        int k = k0 + j;
        float pr = pr4[j];
        float Aqk = (k == q - 1) ? pmq : ((k == q + 1) ? ppq : uniq);
        float Akq = (k == q - 1) ? ppp : ((k == q + 1) ? pmn : uk4[j]);
        float na = pr + (1.f - pr) * sqrtf(Aqk * Akq + NEG_EPS);
        float g;
        if (k == q) {
            g = na;
        } else {
            float dd = (k > q) ? (C4[j] - Cq) : (Cq - C4[j]);
            g = __expf(dd) + NEG_EPS;
        }
        na4[j] = na;
        g4[j]  = g;
    }
    *(f32x4*)(gout + rowoff + k0)  = g4;
    *(f32x4*)(naout + rowoff + k0) = na4;
}

extern "C" void kernel_launch(void* const* d_in, const int* in_sizes, int n_in,
                              void* d_out, int out_size, void* d_ws, size_t ws_size,
                              hipStream_t stream) {
    const float* ctx   = (const float*)d_in[0];
    const int*   eos   = (const int*)d_in[1];
    const float* prior = (const float*)d_in[2];
    const float* Wk    = (const float*)d_in[3];
    const float* bk    = (const float*)d_in[4];
    const float* Wq    = (const float*)d_in[5];
    const float* bq    = (const float*)d_in[6];

    float* gout  = (float*)d_out;
    float* naout = gout + (size_t)BB * SS * SS;

    char* ws = (char*)d_ws;
    __bf16* ctx_bf = (__bf16*)ws;                           // 8 MiB
    __bf16* w_bf   = (__bf16*)(ws + (8u << 20));            // 1 MiB
    __bf16* qk     = (__bf16*)(ws + (9u << 20));            // 16 MiB
    float*  ppb    = (float*)(ws + (25u << 20));            // 32 KiB
    float*  pmb    = ppb + MROWS;
    float*  uniV   = pmb + MROWS;
    float*  Cbuf   = uniV + MROWS;

    f32_to_bf16<<<2048, 256, 0, stream>>>(ctx, ctx_bf, MROWS * DD);
    f32_to_bf16<<<256, 256, 0, stream>>>(Wq, w_bf, DD * DD);
    f32_to_bf16<<<256, 256, 0, stream>>>(Wk, w_bf + DD * DD, DD * DD);

    gemm_qk<<<64 * 8, 256, 0, stream>>>(ctx_bf, w_bf, bq, bk, qk);

    band_softmax<<<MROWS / 4, 256, 0, stream>>>(qk, eos, ppb, pmb, uniV);

    scan_kernel<<<BB, 1024, 0, stream>>>(prior, ppb, pmb, Cbuf);

    fill_kernel<<<MROWS, 256, 0, stream>>>(prior, ppb, pmb, uniV, Cbuf, gout, naout);
}